// Round 2
// baseline (339.011 us; speedup 1.0000x reference)
//
#include <hip/hip_runtime.h>

#define KS 11
#define HK 5
#define TBX 32
#define TBY 32
#define IN_T 42      // TBX + KS - 1
#define IN_ST 44     // padded stride, keeps rows 16B-aligned
#define IMG_H 512
#define IMG_W 512
#define OUT_H 502
#define OUT_W 502
#define N_IMG 64
#define N_SLOTS 256

__global__ void ssim_init(double* __restrict__ acc) { acc[threadIdx.x] = 0.0; }

__global__ __launch_bounds__(256) void ssim_sep(
    const float* __restrict__ g_a, const float* __restrict__ g_b,
    const float* __restrict__ g_w, double* __restrict__ acc)
{
  __shared__ float s_a[IN_T][IN_ST];
  __shared__ float s_b[IN_T][IN_ST];
  __shared__ float s_h[5][IN_T][TBX];
  __shared__ float s_u[16];
  __shared__ float s_red[4];

  const int t = threadIdx.x;
  const int x0 = blockIdx.x * TBX, y0 = blockIdx.y * TBY;
  const size_t base = (size_t)blockIdx.z * (size_t)(IMG_H * IMG_W);
  const float* __restrict__ A = g_a + base;
  const float* __restrict__ B = g_b + base;

  // extract exact rank-1 factor: w[i][j] = u[i]*u[j]
  if (t < KS) s_u[t] = g_w[t * KS + HK] / sqrtf(g_w[HK * KS + HK]);

  // stage 42x42 input tile (both images), zero-fill OOB
  for (int idx = t; idx < IN_T * IN_T; idx += 256) {
    const int r = idx / IN_T, c = idx - r * IN_T;
    const int gy = y0 + r, gx = x0 + c;
    float a = 0.f, b = 0.f;
    if (gy < IMG_H && gx < IMG_W) {
      a = A[gy * IMG_W + gx];
      b = B[gy * IMG_W + gx];
    }
    s_a[r][c] = a;
    s_b[r][c] = b;
  }
  __syncthreads();

  float u[KS];
#pragma unroll
  for (int j = 0; j < KS; ++j) u[j] = s_u[j];

  // horizontal pass: 42 rows x 8 strips of 4 cols -> 5 h-maps [42][32]
  for (int s = t; s < IN_T * 8; s += 256) {
    const int r = s >> 3, c0 = (s & 7) << 2;
    float ea[16], eb[16];
    *(float4*)&ea[0]  = *(const float4*)&s_a[r][c0];
    *(float4*)&ea[4]  = *(const float4*)&s_a[r][c0 + 4];
    *(float4*)&ea[8]  = *(const float4*)&s_a[r][c0 + 8];
    *(float4*)&ea[12] = *(const float4*)&s_a[r][c0 + 12];
    *(float4*)&eb[0]  = *(const float4*)&s_b[r][c0];
    *(float4*)&eb[4]  = *(const float4*)&s_b[r][c0 + 4];
    *(float4*)&eb[8]  = *(const float4*)&s_b[r][c0 + 8];
    *(float4*)&eb[12] = *(const float4*)&s_b[r][c0 + 12];

    float hm1[4], hm2[4], h11[4], h22[4], h12[4];
#pragma unroll
    for (int cc = 0; cc < 4; ++cc) {
      float m1 = 0.f, m2 = 0.f, q11 = 0.f, q22 = 0.f, q12 = 0.f;
#pragma unroll
      for (int j = 0; j < KS; ++j) {
        const float a = ea[cc + j], b = eb[cc + j];
        const float ta = u[j] * a, tb = u[j] * b;
        m1 += ta;
        m2 += tb;
        q11 = fmaf(ta, a, q11);
        q22 = fmaf(tb, b, q22);
        q12 = fmaf(ta, b, q12);
      }
      hm1[cc] = m1; hm2[cc] = m2; h11[cc] = q11; h22[cc] = q22; h12[cc] = q12;
    }
    *(float4*)&s_h[0][r][c0] = make_float4(hm1[0], hm1[1], hm1[2], hm1[3]);
    *(float4*)&s_h[1][r][c0] = make_float4(hm2[0], hm2[1], hm2[2], hm2[3]);
    *(float4*)&s_h[2][r][c0] = make_float4(h11[0], h11[1], h11[2], h11[3]);
    *(float4*)&s_h[3][r][c0] = make_float4(h22[0], h22[1], h22[2], h22[3]);
    *(float4*)&s_h[4][r][c0] = make_float4(h12[0], h12[1], h12[2], h12[3]);
  }
  __syncthreads();

  // vertical pass: each thread does 4 consecutive y at one x
  const int x = t & 31;
  const int yq = (t >> 5) << 2;
  float omu1[4], omu2[4], os11[4], os22[4], os12[4];

  auto vconv = [&](int m, float* o) {
    float v[14];
#pragma unroll
    for (int k = 0; k < 14; ++k) v[k] = s_h[m][yq + k][x];
#pragma unroll
    for (int yy = 0; yy < 4; ++yy) {
      float a_ = 0.f;
#pragma unroll
      for (int i = 0; i < KS; ++i) a_ = fmaf(u[i], v[yy + i], a_);
      o[yy] = a_;
    }
  };
  vconv(0, omu1);
  vconv(1, omu2);
  vconv(2, os11);
  vconv(3, os22);
  vconv(4, os12);

  float score = 0.f;
  const int gx_ = x0 + x;
#pragma unroll
  for (int yy = 0; yy < 4; ++yy) {
    const int gy_ = y0 + yq + yy;
    if (gx_ < OUT_W && gy_ < OUT_H) {
      const float C1 = 1e-4f, C2 = 9e-4f;
      const float mu1 = omu1[yy], mu2 = omu2[yy];
      const float mu1s = mu1 * mu1, mu2s = mu2 * mu2, m12 = mu1 * mu2;
      const float sig1 = os11[yy] - mu1s, sig2 = os22[yy] - mu2s,
                  sig12 = os12[yy] - m12;
      score += ((2.f * m12 + C1) * (2.f * sig12 + C2)) /
               ((mu1s + mu2s + C1) * (sig1 + sig2 + C2));
    }
  }

  // block reduction
#pragma unroll
  for (int off = 32; off > 0; off >>= 1)
    score += __shfl_down(score, off);
  const int wave = t >> 6, lane = t & 63;
  if (lane == 0) s_red[wave] = score;
  __syncthreads();
  if (t == 0) {
    const float bsum = s_red[0] + s_red[1] + s_red[2] + s_red[3];
    const int bid = (int)(blockIdx.z * gridDim.y * gridDim.x +
                          blockIdx.y * gridDim.x + blockIdx.x);
    atomicAdd(&acc[bid & (N_SLOTS - 1)], (double)bsum);
  }
}

__global__ void ssim_final(const double* __restrict__ acc,
                           float* __restrict__ out) {
  double v = acc[threadIdx.x];
#pragma unroll
  for (int off = 32; off > 0; off >>= 1)
    v += __shfl_down(v, off);
  __shared__ double s_red[4];
  const int wave = (int)threadIdx.x >> 6, lane = (int)threadIdx.x & 63;
  if (lane == 0) s_red[wave] = v;
  __syncthreads();
  if (threadIdx.x == 0) {
    const double total = s_red[0] + s_red[1] + s_red[2] + s_red[3];
    out[0] = (float)(total / (double)((size_t)N_IMG * OUT_H * OUT_W));
  }
}

extern "C" void kernel_launch(void* const* d_in, const int* in_sizes, int n_in,
                              void* d_out, int out_size, void* d_ws, size_t ws_size,
                              hipStream_t stream) {
  const float* yh = (const float*)d_in[0];
  const float* yy = (const float*)d_in[1];
  const float* w  = (const float*)d_in[2];
  double* acc = (double*)d_ws;
  float* out = (float*)d_out;

  hipLaunchKernelGGL(ssim_init, dim3(1), dim3(N_SLOTS), 0, stream, acc);

  dim3 grid((OUT_W + TBX - 1) / TBX, (OUT_H + TBY - 1) / TBY, N_IMG);
  hipLaunchKernelGGL(ssim_sep, grid, dim3(256), 0, stream, yh, yy, w, acc);

  hipLaunchKernelGGL(ssim_final, dim3(1), dim3(N_SLOTS), 0, stream, acc, out);
}

// Round 3
// 257.778 us; speedup vs baseline: 1.3151x; 1.3151x over previous
//
#include <hip/hip_runtime.h>

#define KS 11
#define TBX 32
#define TBY 32
#define NROWS 42        // TBY + KS - 1
#define HST 34          // s_h row stride in floats (even -> float2-aligned)
#define IMG 512
#define OUT_H 502
#define OUT_W 502
#define N_IMG 64
#define GXD 16
#define GYD 16
#define NBLK (GXD * GYD * N_IMG)

__global__ __launch_bounds__(256, 4) void ssim_main(
    const float* __restrict__ g_a, const float* __restrict__ g_b,
    const float* __restrict__ g_w, float* __restrict__ bsum)
{
  __shared__ float s_h[5][NROWS][HST];   // 28,560 B
  __shared__ float s_red[4];

  const int t = threadIdx.x;
  const int x0 = blockIdx.x * TBX, y0 = blockIdx.y * TBY;
  const float* __restrict__ A = g_a + (size_t)blockIdx.z * (IMG * IMG);
  const float* __restrict__ B = g_b + (size_t)blockIdx.z * (IMG * IMG);

  // exact rank-1 factor of the Gaussian window: w[i][j] = u[i]*u[j]
  float u[KS];
  {
    const float inv = 1.0f / sqrtf(g_w[5 * KS + 5]);
#pragma unroll
    for (int j = 0; j < KS; ++j) u[j] = g_w[j * KS + 5] * inv;
  }

  // ---- horizontal pass: 42 rows x 6 strips x 6 cols, direct from global ----
  const bool edge = (x0 == IMG - TBX) || (y0 == IMG - TBX);
  if (t < 252) {
    const int r = t / 6;
    const int k = t - r * 6;
    const int c0 = (k == 5) ? 26 : 6 * k;   // strip 5 overlaps 4 (identical dup writes)
    const int gy = y0 + r;
    const int gxs = x0 + c0;

    float ea[16], eb[16];
    if (!edge) {
      // interior: rows/cols gy<=489, gx<=489 — always in-image
      const float* pa = A + gy * IMG + gxs;
      const float* pb = B + gy * IMG + gxs;
#pragma unroll
      for (int i = 0; i < 8; ++i) {
        const float2 va = *(const float2*)(pa + 2 * i);
        const float2 vb = *(const float2*)(pb + 2 * i);
        ea[2 * i] = va.x; ea[2 * i + 1] = va.y;
        eb[2 * i] = vb.x; eb[2 * i + 1] = vb.y;
      }
    } else {
      // edge blocks: per-element clamp; clamped values only reach masked outputs
      const int gyc = min(gy, IMG - 1);
      const float* pa = A + gyc * IMG;
      const float* pb = B + gyc * IMG;
#pragma unroll
      for (int i = 0; i < 16; ++i) {
        const int gx = min(gxs + i, IMG - 1);
        ea[i] = pa[gx];
        eb[i] = pb[gx];
      }
    }

    float hm1[6], hm2[6], h11[6], h22[6], h12[6];
#pragma unroll
    for (int cc = 0; cc < 6; ++cc) {
      float m1 = 0.f, m2 = 0.f, q11 = 0.f, q22 = 0.f, q12 = 0.f;
#pragma unroll
      for (int j = 0; j < KS; ++j) {
        const float a = ea[cc + j], b = eb[cc + j];
        const float ta = u[j] * a, tb = u[j] * b;
        m1 += ta;
        m2 += tb;
        q11 = fmaf(ta, a, q11);
        q22 = fmaf(tb, b, q22);
        q12 = fmaf(ta, b, q12);
      }
      hm1[cc] = m1; hm2[cc] = m2; h11[cc] = q11; h22[cc] = q22; h12[cc] = q12;
    }

#define WRMAP(m, arr)                                                   \
    *(float2*)&s_h[m][r][c0]     = make_float2(arr[0], arr[1]);         \
    *(float2*)&s_h[m][r][c0 + 2] = make_float2(arr[2], arr[3]);         \
    *(float2*)&s_h[m][r][c0 + 4] = make_float2(arr[4], arr[5]);
    WRMAP(0, hm1) WRMAP(1, hm2) WRMAP(2, h11) WRMAP(3, h22) WRMAP(4, h12)
#undef WRMAP
  }
  __syncthreads();

  // ---- vertical pass: thread = (x, 4 consecutive y) ----
  const int x = t & 31;
  const int yq = (t >> 5) << 2;
  float omu1[4], omu2[4], os11[4], os22[4], os12[4];

  auto vconv = [&](int m, float* o) {
    float v[14];
#pragma unroll
    for (int kk = 0; kk < 14; ++kk) v[kk] = s_h[m][yq + kk][x];
#pragma unroll
    for (int yy = 0; yy < 4; ++yy) {
      float a_ = 0.f;
#pragma unroll
      for (int i = 0; i < KS; ++i) a_ = fmaf(u[i], v[yy + i], a_);
      o[yy] = a_;
    }
  };
  vconv(0, omu1);
  vconv(1, omu2);
  vconv(2, os11);
  vconv(3, os22);
  vconv(4, os12);

  float score = 0.f;
  const int gx_ = x0 + x;
#pragma unroll
  for (int yy = 0; yy < 4; ++yy) {
    const int gy_ = y0 + yq + yy;
    if (gx_ < OUT_W && gy_ < OUT_H) {
      const float C1 = 1e-4f, C2 = 9e-4f;
      const float mu1 = omu1[yy], mu2 = omu2[yy];
      const float mu1s = mu1 * mu1, mu2s = mu2 * mu2, m12 = mu1 * mu2;
      const float sig1 = os11[yy] - mu1s, sig2 = os22[yy] - mu2s,
                  sig12 = os12[yy] - m12;
      score += ((2.f * m12 + C1) * (2.f * sig12 + C2)) /
               ((mu1s + mu2s + C1) * (sig1 + sig2 + C2));
    }
  }

  // ---- block reduction -> one float per block (no atomics, no init) ----
#pragma unroll
  for (int off = 32; off > 0; off >>= 1)
    score += __shfl_down(score, off);
  const int wave = t >> 6, lane = t & 63;
  if (lane == 0) s_red[wave] = score;
  __syncthreads();
  if (t == 0) {
    const int bid = (int)((blockIdx.z * GYD + blockIdx.y) * GXD + blockIdx.x);
    bsum[bid] = s_red[0] + s_red[1] + s_red[2] + s_red[3];
  }
}

__global__ __launch_bounds__(256) void ssim_final(
    const float* __restrict__ bsum, float* __restrict__ out)
{
  double v = 0.0;
  for (int i = threadIdx.x; i < NBLK; i += 256) v += (double)bsum[i];
#pragma unroll
  for (int off = 32; off > 0; off >>= 1)
    v += __shfl_down(v, off);
  __shared__ double s_red[4];
  const int wave = (int)threadIdx.x >> 6, lane = (int)threadIdx.x & 63;
  if (lane == 0) s_red[wave] = v;
  __syncthreads();
  if (threadIdx.x == 0) {
    const double total = s_red[0] + s_red[1] + s_red[2] + s_red[3];
    out[0] = (float)(total / (double)((size_t)N_IMG * OUT_H * OUT_W));
  }
}

extern "C" void kernel_launch(void* const* d_in, const int* in_sizes, int n_in,
                              void* d_out, int out_size, void* d_ws, size_t ws_size,
                              hipStream_t stream) {
  const float* yh = (const float*)d_in[0];
  const float* yy = (const float*)d_in[1];
  const float* w  = (const float*)d_in[2];
  float* bsum = (float*)d_ws;          // NBLK floats = 64 KB
  float* out = (float*)d_out;

  dim3 grid(GXD, GYD, N_IMG);
  hipLaunchKernelGGL(ssim_main, grid, dim3(256), 0, stream, yh, yy, w, bsum);
  hipLaunchKernelGGL(ssim_final, dim3(1), dim3(256), 0, stream, bsum, out);
}